// Round 1
// baseline (259.716 us; speedup 1.0000x reference)
//
#include <hip/hip_runtime.h>
#include <math.h>

// DiffKS: differentiable Karplus-Strong resonator.
// Key insight: the (T,544) LPC matrix A is 7-sparse per row with the nonzero
// band starting at z_l[t] >= 100, so y[t] only depends on y[t-101] and older.
// => chunks of 101 samples are internally parallel; 437 chunks, one block.
// Everything (control frames, excitation, history) lives in LDS.

#define T_SAMPLES 44100
#define NFRAMES   100
#define NCOEF     6      // L_ORDER+1
#define NACT      7      // NUM_COEFF+1
#define BURST     2048
#define EXC_ORD   5
#define CHUNK     101    // guaranteed min dependency distance (z_l >= 100)
#define NCH       ((T_SAMPLES + CHUNK - 1) / CHUNK)   // 437
#define HIST      1024   // circular history, need >= 527 back

__global__ __launch_bounds__(128) void diffks_kernel(
    const float* __restrict__ delay_frames,   // (100,)
    const float* __restrict__ excitation,     // (2048,)
    const float* __restrict__ raw_coeff,      // (100,6)
    const float* __restrict__ raw_gain,       // (1,)
    const float* __restrict__ exc_coeff,      // (100,5)
    float* __restrict__ out)                  // (44100,) f32
{
    __shared__ float s_a[EXC_ORD][BURST];                 // 40 KB exc LPC coeffs
    __shared__ float s_x[BURST];                          // 8 KB excitation -> filtered burst
    __shared__ float s_hist[HIST];                        // 4 KB circular y history
    __shared__ __align__(16) float s_coef[NFRAMES][8];    // 3.2 KB normalized loop coeffs (padded to 8)
    __shared__ float s_delay[NFRAMES];                    // 0.4 KB

    const int tid = threadIdx.x;

    // gain = sigmoid(raw_gain)*0.1 + 0.9  (uniform across threads)
    const float gain = 0.1f / (1.0f + expf(-raw_gain[0])) + 0.9f;

    // ---- Phase 0: stage control data into LDS (parallel) ----
    for (int i = tid; i < NFRAMES; i += 128)
        s_delay[i] = delay_frames[i];

    // per-frame: coeff = sigmoid(raw) / sum * gain
    for (int f = tid; f < NFRAMES; f += 128) {
        float sb[NCOEF];
        float s = 0.0f;
        #pragma unroll
        for (int j = 0; j < NCOEF; ++j) {
            sb[j] = 1.0f / (1.0f + expf(-raw_coeff[f * NCOEF + j]));
            s += sb[j];
        }
        float inv = gain / s;
        #pragma unroll
        for (int j = 0; j < NCOEF; ++j)
            s_coef[f][j] = sb[j] * inv;
        s_coef[f][6] = 0.0f;
        s_coef[f][7] = 0.0f;
    }

    // excitation-LPC coefficients: upsample_linear(exc_coefficients, 2048)
    const float stepE = 99.0f / 2047.0f;
    for (int t = tid; t < BURST; t += 128) {
        float pos = (float)t * stepE;
        int i0 = (int)pos;            // pos >= 0, trunc == floor
        if (i0 > NFRAMES - 2) i0 = NFRAMES - 2;
        float w = pos - (float)i0;
        const float* c0 = exc_coeff + i0 * EXC_ORD;
        #pragma unroll
        for (int k = 0; k < EXC_ORD; ++k) {
            float a0 = c0[k];
            float a1 = c0[k + EXC_ORD];
            s_a[k][t] = a0 + (a1 - a0) * w;
        }
        s_x[t] = excitation[t];
    }

    // zero circular history (represents y[t<0] = 0)
    for (int i = tid; i < HIST; i += 128)
        s_hist[i] = 0.0f;

    __syncthreads();

    // ---- Phase 1: serial order-5 excitation LPC (lane 0) ----
    // y[t] = x[t] - sum_k a[t,k]*y[t-1-k]; restructured so the loop-carried
    // critical path is a single fma off y[t-1].
    if (tid == 0) {
        float y1 = 0.f, y2 = 0.f, y3 = 0.f, y4 = 0.f, y5 = 0.f;
        #pragma unroll 4
        for (int t = 0; t < BURST; ++t) {
            float p = s_x[t];
            p = fmaf(-s_a[1][t], y2, p);
            p = fmaf(-s_a[2][t], y3, p);
            p = fmaf(-s_a[3][t], y4, p);
            p = fmaf(-s_a[4][t], y5, p);
            float y = fmaf(-s_a[0][t], y1, p);
            s_x[t] = y;
            y5 = y4; y4 = y3; y3 = y2; y2 = y1; y1 = y;
        }
    }
    __syncthreads();

    // ---- Phase 2: main Karplus-Strong loop, 437 chunks of 101 ----
    const float stepT = 99.0f / (float)(T_SAMPLES - 1);
    for (int c = 0; c < NCH; ++c) {
        int t = c * CHUNK + tid;
        if (tid < CHUNK && t < T_SAMPLES) {
            // recompute per-sample coefficients from LDS-staged frames
            float pos = (float)t * stepT;
            int i0 = (int)pos;
            if (i0 > NFRAMES - 2) i0 = NFRAMES - 2;
            float w = pos - (float)i0;

            float d0 = s_delay[i0];
            float d1 = s_delay[i0 + 1];
            float delay = d0 + (d1 - d0) * w;
            int z = (int)delay;                 // floor, delay > 0
            float alfa = delay - (float)z;

            const float4* f0 = reinterpret_cast<const float4*>(s_coef[i0]);
            const float4* f1 = reinterpret_cast<const float4*>(s_coef[i0 + 1]);
            float4 c0a = f0[0], c0b = f0[1];
            float4 c1a = f1[0], c1b = f1[1];

            float b[NCOEF];
            b[0] = c0a.x + (c1a.x - c0a.x) * w;
            b[1] = c0a.y + (c1a.y - c0a.y) * w;
            b[2] = c0a.z + (c1a.z - c0a.z) * w;
            b[3] = c0a.w + (c1a.w - c0a.w) * w;
            b[4] = c0b.x + (c1b.x - c0b.x) * w;
            b[5] = c0b.y + (c1b.y - c0b.y) * w;

            float oma = 1.0f - alfa;
            float v[NACT];
            v[0] = -oma * b[0];
            #pragma unroll
            for (int j = 1; j <= 5; ++j)
                v[j] = -(alfa * b[j - 1] + oma * b[j]);
            v[6] = -alfa * b[5];

            float x = (t < BURST) ? s_x[t] : 0.0f;

            int base = t - z - 1;               // <= t-101: previous chunks only
            float sum = 0.0f;
            #pragma unroll
            for (int j = 0; j < NACT; ++j) {
                int idx = base - j;
                float yv = s_hist[idx & (HIST - 1)];
                if (idx < 0) yv = 0.0f;         // y[t<0] = 0
                sum = fmaf(v[j], yv, sum);
            }
            float y = x - sum;
            s_hist[t & (HIST - 1)] = y;
            out[t] = y;
        }
        __syncthreads();
    }
}

extern "C" void kernel_launch(void* const* d_in, const int* in_sizes, int n_in,
                              void* d_out, int out_size, void* d_ws, size_t ws_size,
                              hipStream_t stream) {
    const float* delay_frames = (const float*)d_in[0];
    const float* excitation   = (const float*)d_in[1];
    const float* raw_coeff    = (const float*)d_in[2];
    const float* raw_gain     = (const float*)d_in[3];
    const float* exc_coeff    = (const float*)d_in[4];
    // d_in[5] = n_samples (int32) == 44100, compile-time constant here
    float* out = (float*)d_out;

    diffks_kernel<<<1, 128, 0, stream>>>(delay_frames, excitation, raw_coeff,
                                         raw_gain, exc_coeff, out);
}

// Round 2
// 212.730 us; speedup vs baseline: 1.2209x; 1.2209x over previous
//
#include <hip/hip_runtime.h>
#include <math.h>

// DiffKS round 2.
// Kernel A (parallel): precompute per-sample sparse-LPC coefficients v[0..6]
//   and band base index into d_ws; also interpolate excitation-LPC coeffs.
// Kernel B (1 wave):  barrier-free serial resonator. K=50 chunks (z>=100=2K
//   => chunk c+2 only needs writes <= chunk c), software-pipelined:
//   hist reads for c+2 issued right after write of c; coef global loads in a
//   depth-16 register ring. Excitation LPC parallelized via 64-segment
//   state-space scan (particular + 5 homogeneous responses, 5x5 combine).

#define T_SAMPLES 44100
#define NFRAMES   100
#define NCOEF     6
#define NACT      7
#define BURST     2048
#define EXC_ORD   5
#define K50       50
#define NCHUNK    882            // 882*50 = 44100 exactly
#define UNROLL    16
#define NCHPAD    896            // 56*16
#define HISTSZ    1032           // 1024 ring + 7 mirror + pad

#define WS_COEF_FLOATS (T_SAMPLES * 8)      // v0..v6 + base (as int), 32B/sample
#define WS_EXC_OFF     WS_COEF_FLOATS
#define WS_EXC_FLOATS  (EXC_ORD * BURST)
#define WS_TOTAL_BYTES ((size_t)(WS_COEF_FLOATS + WS_EXC_FLOATS) * 4)

// ---------------------------------------------------------------- kernel A
__global__ __launch_bounds__(256) void diffks_precompute(
    const float* __restrict__ delay_frames,
    const float* __restrict__ raw_coeff,
    const float* __restrict__ raw_gain,
    const float* __restrict__ exc_coeff,
    float* __restrict__ ws)
{
    int g = blockIdx.x * 256 + threadIdx.x;
    const float gain = 0.1f / (1.0f + expf(-raw_gain[0])) + 0.9f;

    if (g < T_SAMPLES) {
        const float stepT = 99.0f / (float)(T_SAMPLES - 1);
        float pos = (float)g * stepT;
        int i0 = (int)pos; if (i0 > NFRAMES - 2) i0 = NFRAMES - 2;
        float w = pos - (float)i0;

        float d0 = delay_frames[i0], d1 = delay_frames[i0 + 1];
        float delay = d0 + (d1 - d0) * w;
        int z = (int)delay;                  // delay >= 100 > 0, trunc==floor
        float alfa = delay - (float)z;

        float b[NCOEF];
        {
            float c0v[NCOEF], c1v[NCOEF];
            float s0 = 0.f, s1 = 0.f;
            #pragma unroll
            for (int j = 0; j < NCOEF; ++j) {
                c0v[j] = 1.0f / (1.0f + expf(-raw_coeff[i0 * NCOEF + j]));
                c1v[j] = 1.0f / (1.0f + expf(-raw_coeff[(i0 + 1) * NCOEF + j]));
                s0 += c0v[j]; s1 += c1v[j];
            }
            float g0 = gain / s0, g1 = gain / s1;
            #pragma unroll
            for (int j = 0; j < NCOEF; ++j) {
                float x0 = c0v[j] * g0, x1 = c1v[j] * g1;
                b[j] = x0 + (x1 - x0) * w;
            }
        }
        float oma = 1.0f - alfa;
        float v0 = -oma * b[0];
        float v1 = -(alfa * b[0] + oma * b[1]);
        float v2 = -(alfa * b[1] + oma * b[2]);
        float v3 = -(alfa * b[2] + oma * b[3]);
        float v4 = -(alfa * b[3] + oma * b[4]);
        float v5 = -(alfa * b[4] + oma * b[5]);
        float v6 = -alfa * b[5];
        int base = g - z - 1;

        float4* o = (float4*)(ws + (size_t)g * 8);
        o[0] = make_float4(v0, v1, v2, v3);
        o[1] = make_float4(v4, v5, v6, __int_as_float(base));
    } else if (g < T_SAMPLES + BURST) {
        int te = g - T_SAMPLES;
        const float stepE = 99.0f / (float)(BURST - 1);
        float pos = (float)te * stepE;
        int i0 = (int)pos; if (i0 > NFRAMES - 2) i0 = NFRAMES - 2;
        float w = pos - (float)i0;
        #pragma unroll
        for (int k = 0; k < EXC_ORD; ++k) {
            float a0 = exc_coeff[i0 * EXC_ORD + k];
            float a1 = exc_coeff[(i0 + 1) * EXC_ORD + k];
            ws[WS_EXC_OFF + k * BURST + te] = a0 + (a1 - a0) * w;
        }
    }
}

// ---------------------------------------------------------------- kernel B
__global__ __launch_bounds__(64) void diffks_serial(
    const float* __restrict__ excitation,
    const float* __restrict__ ws,
    float* __restrict__ out)
{
    __shared__ float s_x[64][33];        // burst, padded (lane stride 33 ≡ 1 mod 32)
    __shared__ float s_a[64][161];       // exc coefs per 32-seg, [seg][(i%32)*5+k]
    __shared__ float s_hist[HISTSZ];     // 1024 ring + 7 mirror
    __shared__ float s_tail[64][32];     // scan tails: [lane][r*5+k]
    __shared__ float s_bound[64][6];     // boundary states per segment

    const int lane = threadIdx.x;

    // ---- stage ----
    for (int t = lane; t < BURST; t += 64)
        s_x[t >> 5][t & 31] = excitation[t];
    for (int idx = lane; idx < WS_EXC_FLOATS; idx += 64) {
        int k = idx >> 11;           // / 2048
        int t = idx & 2047;
        s_a[t >> 5][(t & 31) * 5 + k] = ws[WS_EXC_OFF + idx];
    }
    for (int i = lane; i < HISTSZ; i += 64) s_hist[i] = 0.0f;
    __syncthreads();   // single wave: near-free

    // ---- phase 1: excitation LPC via 64-segment state-space scan ----
    // pass 1: per segment, particular (zero init) + 5 homogeneous responses
    {
        float st[6][5];
        #pragma unroll
        for (int r = 0; r < 6; ++r)
            #pragma unroll
            for (int k = 0; k < 5; ++k) st[r][k] = 0.0f;
        #pragma unroll
        for (int r = 1; r <= 5; ++r) st[r][r - 1] = 1.0f;

        const float* ar = &s_a[lane][0];
        const float* xr = &s_x[lane][0];
        #pragma unroll 8
        for (int i = 0; i < 32; ++i) {
            float a0 = ar[i * 5 + 0], a1 = ar[i * 5 + 1], a2 = ar[i * 5 + 2];
            float a3 = ar[i * 5 + 3], a4 = ar[i * 5 + 4];
            float xv = xr[i];
            #pragma unroll
            for (int r = 0; r < 6; ++r) {
                float acc = (r == 0) ? xv : 0.0f;
                acc = fmaf(-a0, st[r][0], acc);
                acc = fmaf(-a1, st[r][1], acc);
                acc = fmaf(-a2, st[r][2], acc);
                acc = fmaf(-a3, st[r][3], acc);
                acc = fmaf(-a4, st[r][4], acc);
                st[r][4] = st[r][3]; st[r][3] = st[r][2];
                st[r][2] = st[r][1]; st[r][1] = st[r][0];
                st[r][0] = acc;
            }
        }
        #pragma unroll
        for (int r = 0; r < 6; ++r)
            #pragma unroll
            for (int k = 0; k < 5; ++k)
                s_tail[lane][r * 5 + k] = st[r][k];
    }
    __syncthreads();

    // pass 2: lane 0 serially chains 5-dim boundary states through 64 segments
    if (lane == 0) {
        float Y[5] = {0.f, 0.f, 0.f, 0.f, 0.f};
        for (int l = 0; l < 64; ++l) {
            #pragma unroll
            for (int c = 0; c < 5; ++c) s_bound[l][c] = Y[c];
            float tl[30];
            #pragma unroll
            for (int j = 0; j < 30; ++j) tl[j] = s_tail[l][j];
            float ny[5];
            #pragma unroll
            for (int k = 0; k < 5; ++k) {
                float acc = tl[k];                       // particular final
                #pragma unroll
                for (int c = 1; c <= 5; ++c)             // + homog * init
                    acc = fmaf(tl[c * 5 + k], Y[c - 1], acc);
                ny[k] = acc;
            }
            #pragma unroll
            for (int k = 0; k < 5; ++k) Y[k] = ny[k];
        }
    }
    __syncthreads();

    // pass 3: re-run each segment with the correct boundary state
    {
        float b0 = s_bound[lane][0], b1 = s_bound[lane][1], b2 = s_bound[lane][2];
        float b3 = s_bound[lane][3], b4 = s_bound[lane][4];
        const float* ar = &s_a[lane][0];
        float* xr = &s_x[lane][0];
        #pragma unroll 8
        for (int i = 0; i < 32; ++i) {
            float a0 = ar[i * 5 + 0], a1 = ar[i * 5 + 1], a2 = ar[i * 5 + 2];
            float a3 = ar[i * 5 + 3], a4 = ar[i * 5 + 4];
            float acc = xr[i];
            acc = fmaf(-a0, b0, acc);
            acc = fmaf(-a1, b1, acc);
            acc = fmaf(-a2, b2, acc);
            acc = fmaf(-a3, b3, acc);
            acc = fmaf(-a4, b4, acc);
            b4 = b3; b3 = b2; b2 = b1; b1 = b0; b0 = acc;
            xr[i] = acc;                 // filtered burst back into s_x
        }
    }
    __syncthreads();

    // ---- phase 2: barrier-free pipelined resonator ----
    const float4* cw = (const float4*)ws;     // 2x float4 per sample
    const bool lane_act = (lane < K50);

    float4 cA[UNROLL], cB[UNROLL];
    #pragma unroll
    for (int u = 0; u < UNROLL; ++u) {
        int t = u * K50 + lane; if (t > T_SAMPLES - 1) t = T_SAMPLES - 1;
        cA[u] = cw[t * 2 + 0];
        cB[u] = cw[t * 2 + 1];
    }

    float hvA[7], hvB[7];   // hist values for chunk c (read at body c-2)
    #pragma unroll
    for (int k = 0; k < 7; ++k) { hvA[k] = 0.f; hvB[k] = 0.f; }
    // chunks 0 and 1: all hist deps have idx<0 => contribution 0. hv=0 is exact.

    auto doChunk = [&](int c, const float4& a, const float4& b,
                       const float4& b2, float (&hu)[7]) {
        int t0 = c * K50;
        int t  = t0 + lane;
        // A: y = x - sum v[j]*y[idx]; hu[k] is ring[base-6+k] => pairs v[6-k]
        float xv = 0.0f;
        if (t0 < BURST) {                             // scalar branch, 41 chunks
            xv = (lane_act && t < BURST) ? s_x[t >> 5][t & 31] : 0.0f;
        }
        float acc = xv;
        acc = fmaf(-a.x, hu[6], acc);
        acc = fmaf(-a.y, hu[5], acc);
        acc = fmaf(-a.z, hu[4], acc);
        acc = fmaf(-a.w, hu[3], acc);
        acc = fmaf(-b.x, hu[2], acc);
        acc = fmaf(-b.y, hu[1], acc);
        acc = fmaf(-b.z, hu[0], acc);
        // B: commit chunk c
        if (c < NCHUNK) {
            if (lane_act) {
                unsigned p = ((unsigned)t) & 1023u;
                s_hist[p] = acc;
                unsigned pm = ((unsigned)t0) & 1023u;  // uniform: scalar guard
                if (pm >= 975u || pm < 7u) {
                    if (p < 7u) s_hist[p + 1024u] = acc;   // mirror for wrap
                }
                out[t] = acc;
            }
        }
        // C: issue hist reads for chunk c+2 (needs writes <= c: just done)
        int nbase = __float_as_int(b2.w);
        unsigned q = ((unsigned)(nbase - 6)) & 1023u;
        #pragma unroll
        for (int k = 0; k < 7; ++k) hu[k] = s_hist[q + k];
    };

    for (int i = 0; i < NCHPAD / UNROLL; ++i) {
        int cbase = i * UNROLL;
        #pragma unroll
        for (int v = 0; v < UNROLL; v += 2) {
            doChunk(cbase + v,     cA[v],     cB[v],     cB[(v + 2) & 15], hvA);
            doChunk(cbase + v + 1, cA[v + 1], cB[v + 1], cB[(v + 3) & 15], hvB);
            // reload slots v, v+1 <- chunks +16 (arrive in ~15 bodies)
            int tn0 = (cbase + v + UNROLL) * K50 + lane;
            if (tn0 > T_SAMPLES - 1) tn0 = T_SAMPLES - 1;
            cA[v] = cw[tn0 * 2 + 0];
            cB[v] = cw[tn0 * 2 + 1];
            int tn1 = (cbase + v + 1 + UNROLL) * K50 + lane;
            if (tn1 > T_SAMPLES - 1) tn1 = T_SAMPLES - 1;
            cA[v + 1] = cw[tn1 * 2 + 0];
            cB[v + 1] = cw[tn1 * 2 + 1];
        }
    }
}

// ------------------------------------------------- fallback (round-1 kernel)
#define CHUNK_FB  101
#define NCH_FB    ((T_SAMPLES + CHUNK_FB - 1) / CHUNK_FB)
#define HIST_FB   1024

__global__ __launch_bounds__(128) void diffks_fallback(
    const float* __restrict__ delay_frames,
    const float* __restrict__ excitation,
    const float* __restrict__ raw_coeff,
    const float* __restrict__ raw_gain,
    const float* __restrict__ exc_coeff,
    float* __restrict__ out)
{
    __shared__ float s_a[EXC_ORD][BURST];
    __shared__ float s_x[BURST];
    __shared__ float s_hist[HIST_FB];
    __shared__ __align__(16) float s_coef[NFRAMES][8];
    __shared__ float s_delay[NFRAMES];

    const int tid = threadIdx.x;
    const float gain = 0.1f / (1.0f + expf(-raw_gain[0])) + 0.9f;

    for (int i = tid; i < NFRAMES; i += 128) s_delay[i] = delay_frames[i];
    for (int f = tid; f < NFRAMES; f += 128) {
        float sb[NCOEF]; float s = 0.0f;
        #pragma unroll
        for (int j = 0; j < NCOEF; ++j) {
            sb[j] = 1.0f / (1.0f + expf(-raw_coeff[f * NCOEF + j]));
            s += sb[j];
        }
        float inv = gain / s;
        #pragma unroll
        for (int j = 0; j < NCOEF; ++j) s_coef[f][j] = sb[j] * inv;
        s_coef[f][6] = 0.0f; s_coef[f][7] = 0.0f;
    }
    const float stepE = 99.0f / 2047.0f;
    for (int t = tid; t < BURST; t += 128) {
        float pos = (float)t * stepE;
        int i0 = (int)pos; if (i0 > NFRAMES - 2) i0 = NFRAMES - 2;
        float w = pos - (float)i0;
        const float* c0 = exc_coeff + i0 * EXC_ORD;
        #pragma unroll
        for (int k = 0; k < EXC_ORD; ++k) {
            float a0 = c0[k], a1 = c0[k + EXC_ORD];
            s_a[k][t] = a0 + (a1 - a0) * w;
        }
        s_x[t] = excitation[t];
    }
    for (int i = tid; i < HIST_FB; i += 128) s_hist[i] = 0.0f;
    __syncthreads();

    if (tid == 0) {
        float y1 = 0.f, y2 = 0.f, y3 = 0.f, y4 = 0.f, y5 = 0.f;
        #pragma unroll 4
        for (int t = 0; t < BURST; ++t) {
            float p = s_x[t];
            p = fmaf(-s_a[1][t], y2, p);
            p = fmaf(-s_a[2][t], y3, p);
            p = fmaf(-s_a[3][t], y4, p);
            p = fmaf(-s_a[4][t], y5, p);
            float y = fmaf(-s_a[0][t], y1, p);
            s_x[t] = y;
            y5 = y4; y4 = y3; y3 = y2; y2 = y1; y1 = y;
        }
    }
    __syncthreads();

    const float stepT = 99.0f / (float)(T_SAMPLES - 1);
    for (int c = 0; c < NCH_FB; ++c) {
        int t = c * CHUNK_FB + tid;
        if (tid < CHUNK_FB && t < T_SAMPLES) {
            float pos = (float)t * stepT;
            int i0 = (int)pos; if (i0 > NFRAMES - 2) i0 = NFRAMES - 2;
            float w = pos - (float)i0;
            float d0 = s_delay[i0], d1 = s_delay[i0 + 1];
            float delay = d0 + (d1 - d0) * w;
            int z = (int)delay;
            float alfa = delay - (float)z;
            const float4* f0 = reinterpret_cast<const float4*>(s_coef[i0]);
            const float4* f1 = reinterpret_cast<const float4*>(s_coef[i0 + 1]);
            float4 c0a = f0[0], c0b = f0[1];
            float4 c1a = f1[0], c1b = f1[1];
            float b[NCOEF];
            b[0] = c0a.x + (c1a.x - c0a.x) * w;
            b[1] = c0a.y + (c1a.y - c0a.y) * w;
            b[2] = c0a.z + (c1a.z - c0a.z) * w;
            b[3] = c0a.w + (c1a.w - c0a.w) * w;
            b[4] = c0b.x + (c1b.x - c0b.x) * w;
            b[5] = c0b.y + (c1b.y - c0b.y) * w;
            float oma = 1.0f - alfa;
            float v[NACT];
            v[0] = -oma * b[0];
            #pragma unroll
            for (int j = 1; j <= 5; ++j) v[j] = -(alfa * b[j - 1] + oma * b[j]);
            v[6] = -alfa * b[5];
            float x = (t < BURST) ? s_x[t] : 0.0f;
            int base = t - z - 1;
            float sum = 0.0f;
            #pragma unroll
            for (int j = 0; j < NACT; ++j) {
                int idx = base - j;
                float yv = s_hist[idx & (HIST_FB - 1)];
                if (idx < 0) yv = 0.0f;
                sum = fmaf(v[j], yv, sum);
            }
            float y = x - sum;
            s_hist[t & (HIST_FB - 1)] = y;
            out[t] = y;
        }
        __syncthreads();
    }
}

// ---------------------------------------------------------------- launch
extern "C" void kernel_launch(void* const* d_in, const int* in_sizes, int n_in,
                              void* d_out, int out_size, void* d_ws, size_t ws_size,
                              hipStream_t stream) {
    const float* delay_frames = (const float*)d_in[0];
    const float* excitation   = (const float*)d_in[1];
    const float* raw_coeff    = (const float*)d_in[2];
    const float* raw_gain     = (const float*)d_in[3];
    const float* exc_coeff    = (const float*)d_in[4];
    float* out = (float*)d_out;

    if (ws_size >= WS_TOTAL_BYTES) {
        float* ws = (float*)d_ws;
        int gridA = (T_SAMPLES + BURST + 255) / 256;
        diffks_precompute<<<gridA, 256, 0, stream>>>(delay_frames, raw_coeff,
                                                     raw_gain, exc_coeff, ws);
        diffks_serial<<<1, 64, 0, stream>>>(excitation, ws, out);
    } else {
        diffks_fallback<<<1, 128, 0, stream>>>(delay_frames, excitation,
                                               raw_coeff, raw_gain, exc_coeff, out);
    }
}

// Round 3
// 190.780 us; speedup vs baseline: 1.3613x; 1.1151x over previous
//
#include <hip/hip_runtime.h>
#include <math.h>

// DiffKS round 3.
// Kernel A (parallel): per-sample sparse-LPC coefficients v[0..6] + band base
//   into ws; exc-LPC coeffs interleaved [t*5+k].
// Kernel B (1 wave, __launch_bounds__(64,1)): barrier-free resonator.
//   CHUNK=49 (2*49=98 < 101 min dep distance => 2-ahead LDS pipelining),
//   900 bodies = 75 x 12, coefficient register ring D=12 (96 VGPRs, static
//   indexing via full unroll; occupancy irrelevant for a single wave).

#define T_SAMPLES 44100
#define NFRAMES   100
#define NCOEF     6
#define NACT      7
#define BURST     2048
#define EXC_ORD   5
#define KC        49
#define NB        900           // 900*49 = 44100
#define DRING     12
#define HISTSZ    1032          // 1024 ring + 7 mirror + pad

#define WS_COEF_FLOATS (T_SAMPLES * 8)
#define WS_EXC_OFF     WS_COEF_FLOATS
#define WS_EXC_FLOATS  (EXC_ORD * BURST)
#define WS_TOTAL_BYTES ((size_t)(WS_COEF_FLOATS + WS_EXC_FLOATS) * 4)

// ---------------------------------------------------------------- kernel A
__global__ __launch_bounds__(256) void diffks_precompute(
    const float* __restrict__ delay_frames,
    const float* __restrict__ raw_coeff,
    const float* __restrict__ raw_gain,
    const float* __restrict__ exc_coeff,
    float* __restrict__ ws)
{
    int g = blockIdx.x * 256 + threadIdx.x;
    const float gain = 0.1f / (1.0f + expf(-raw_gain[0])) + 0.9f;

    if (g < T_SAMPLES) {
        const float stepT = 99.0f / (float)(T_SAMPLES - 1);
        float pos = (float)g * stepT;
        int i0 = (int)pos; if (i0 > NFRAMES - 2) i0 = NFRAMES - 2;
        float w = pos - (float)i0;

        float d0 = delay_frames[i0], d1 = delay_frames[i0 + 1];
        float delay = d0 + (d1 - d0) * w;
        int z = (int)delay;                  // delay >= 100 > 0
        float alfa = delay - (float)z;

        float b[NCOEF];
        {
            float c0v[NCOEF], c1v[NCOEF];
            float s0 = 0.f, s1 = 0.f;
            #pragma unroll
            for (int j = 0; j < NCOEF; ++j) {
                c0v[j] = 1.0f / (1.0f + expf(-raw_coeff[i0 * NCOEF + j]));
                c1v[j] = 1.0f / (1.0f + expf(-raw_coeff[(i0 + 1) * NCOEF + j]));
                s0 += c0v[j]; s1 += c1v[j];
            }
            float g0 = gain / s0, g1 = gain / s1;
            #pragma unroll
            for (int j = 0; j < NCOEF; ++j) {
                float x0 = c0v[j] * g0, x1 = c1v[j] * g1;
                b[j] = x0 + (x1 - x0) * w;
            }
        }
        float oma = 1.0f - alfa;
        float v0 = -oma * b[0];
        float v1 = -(alfa * b[0] + oma * b[1]);
        float v2 = -(alfa * b[1] + oma * b[2]);
        float v3 = -(alfa * b[2] + oma * b[3]);
        float v4 = -(alfa * b[3] + oma * b[4]);
        float v5 = -(alfa * b[4] + oma * b[5]);
        float v6 = -alfa * b[5];
        int base = g - z - 1;

        float4* o = (float4*)(ws + (size_t)g * 8);
        o[0] = make_float4(v0, v1, v2, v3);
        o[1] = make_float4(v4, v5, v6, __int_as_float(base));
    } else if (g < T_SAMPLES + BURST) {
        int te = g - T_SAMPLES;
        const float stepE = 99.0f / (float)(BURST - 1);
        float pos = (float)te * stepE;
        int i0 = (int)pos; if (i0 > NFRAMES - 2) i0 = NFRAMES - 2;
        float w = pos - (float)i0;
        float* o = ws + WS_EXC_OFF + te * EXC_ORD;     // interleaved [t*5+k]
        #pragma unroll
        for (int k = 0; k < EXC_ORD; ++k) {
            float a0 = exc_coeff[i0 * EXC_ORD + k];
            float a1 = exc_coeff[(i0 + 1) * EXC_ORD + k];
            o[k] = a0 + (a1 - a0) * w;
        }
    }
}

// ---------------------------------------------------------------- kernel B
__global__ __launch_bounds__(64, 1) void diffks_serial(
    const float* __restrict__ excitation,
    const float* __restrict__ ws,
    float* __restrict__ out)
{
    __shared__ float s_x[64][33];        // burst (padded rows)
    __shared__ float s_a[64][161];       // exc coefs [seg][(i%32)*5+k]
    __shared__ float s_hist[HISTSZ];     // 1024 ring + 7 mirror
    __shared__ float s_tail[64][32];
    __shared__ float s_bound[64][6];

    const int lane = threadIdx.x;

    // ---- stage ----
    for (int t = lane; t < BURST; t += 64)
        s_x[t >> 5][t & 31] = excitation[t];
    {   // exc coefs: lane handles t = lane + 64*i, 5 contiguous scalars each
        for (int i = 0; i < 32; ++i) {
            int t = lane + i * 64;
            const float* g = ws + WS_EXC_OFF + t * EXC_ORD;
            float* dst = &s_a[t >> 5][(t & 31) * 5];
            dst[0] = g[0]; dst[1] = g[1]; dst[2] = g[2];
            dst[3] = g[3]; dst[4] = g[4];
        }
    }
    for (int i = lane; i < HISTSZ; i += 64) s_hist[i] = 0.0f;
    __syncthreads();

    // ---- phase 1: excitation LPC via 64-segment state-space scan ----
    {
        float st[6][5];
        #pragma unroll
        for (int r = 0; r < 6; ++r)
            #pragma unroll
            for (int k = 0; k < 5; ++k) st[r][k] = 0.0f;
        #pragma unroll
        for (int r = 1; r <= 5; ++r) st[r][r - 1] = 1.0f;

        const float* ar = &s_a[lane][0];
        const float* xr = &s_x[lane][0];
        #pragma unroll 8
        for (int i = 0; i < 32; ++i) {
            float a0 = ar[i * 5 + 0], a1 = ar[i * 5 + 1], a2 = ar[i * 5 + 2];
            float a3 = ar[i * 5 + 3], a4 = ar[i * 5 + 4];
            float xv = xr[i];
            #pragma unroll
            for (int r = 0; r < 6; ++r) {
                float acc = (r == 0) ? xv : 0.0f;
                acc = fmaf(-a0, st[r][0], acc);
                acc = fmaf(-a1, st[r][1], acc);
                acc = fmaf(-a2, st[r][2], acc);
                acc = fmaf(-a3, st[r][3], acc);
                acc = fmaf(-a4, st[r][4], acc);
                st[r][4] = st[r][3]; st[r][3] = st[r][2];
                st[r][2] = st[r][1]; st[r][1] = st[r][0];
                st[r][0] = acc;
            }
        }
        #pragma unroll
        for (int r = 0; r < 6; ++r)
            #pragma unroll
            for (int k = 0; k < 5; ++k)
                s_tail[lane][r * 5 + k] = st[r][k];
    }
    __syncthreads();

    if (lane == 0) {   // chain 5-dim boundary states through 64 segments
        float Y[5] = {0.f, 0.f, 0.f, 0.f, 0.f};
        for (int l = 0; l < 64; ++l) {
            #pragma unroll
            for (int c = 0; c < 5; ++c) s_bound[l][c] = Y[c];
            float tl[30];
            #pragma unroll
            for (int j = 0; j < 30; ++j) tl[j] = s_tail[l][j];
            float ny[5];
            #pragma unroll
            for (int k = 0; k < 5; ++k) {
                float acc = tl[k];
                #pragma unroll
                for (int c = 1; c <= 5; ++c)
                    acc = fmaf(tl[c * 5 + k], Y[c - 1], acc);
                ny[k] = acc;
            }
            #pragma unroll
            for (int k = 0; k < 5; ++k) Y[k] = ny[k];
        }
    }
    __syncthreads();

    {   // re-run each segment with correct boundary state
        float b0 = s_bound[lane][0], b1 = s_bound[lane][1], b2 = s_bound[lane][2];
        float b3 = s_bound[lane][3], b4 = s_bound[lane][4];
        const float* ar = &s_a[lane][0];
        float* xr = &s_x[lane][0];
        #pragma unroll 8
        for (int i = 0; i < 32; ++i) {
            float a0 = ar[i * 5 + 0], a1 = ar[i * 5 + 1], a2 = ar[i * 5 + 2];
            float a3 = ar[i * 5 + 3], a4 = ar[i * 5 + 4];
            float acc = xr[i];
            acc = fmaf(-a0, b0, acc);
            acc = fmaf(-a1, b1, acc);
            acc = fmaf(-a2, b2, acc);
            acc = fmaf(-a3, b3, acc);
            acc = fmaf(-a4, b4, acc);
            b4 = b3; b3 = b2; b2 = b1; b1 = b0; b0 = acc;
            xr[i] = acc;
        }
    }
    __syncthreads();

    // ---- phase 2: barrier-free pipelined resonator ----
    const float4* cw = (const float4*)ws;
    const bool lane_act = (lane < KC);

    float4 CF[DRING][2];
    #pragma unroll
    for (int s = 0; s < DRING; ++s) {
        int t = s * KC + lane;
        CF[s][0] = cw[t * 2 + 0];
        CF[s][1] = cw[t * 2 + 1];
    }

    float hu[2][7];
    #pragma unroll
    for (int k = 0; k < 7; ++k) { hu[0][k] = 0.f; hu[1][k] = 0.f; }

    // body: chunk cc (== cb + j, slot j since cb % 12 == 0)
    #define KS_BODY(cc, j, WITHX)                                              \
    {                                                                          \
        const float4 a = CF[j][0];                                             \
        const float4 b = CF[j][1];                                             \
        int t = (cc) * KC + lane;                                              \
        float acc;                                                             \
        if (WITHX) {                                                           \
            acc = (lane_act && t < BURST) ? s_x[t >> 5][t & 31] : 0.0f;        \
        } else acc = 0.0f;                                                     \
        acc = fmaf(-a.x, hu[(j) & 1][6], acc);                                 \
        acc = fmaf(-a.y, hu[(j) & 1][5], acc);                                 \
        acc = fmaf(-a.z, hu[(j) & 1][4], acc);                                 \
        acc = fmaf(-a.w, hu[(j) & 1][3], acc);                                 \
        acc = fmaf(-b.x, hu[(j) & 1][2], acc);                                 \
        acc = fmaf(-b.y, hu[(j) & 1][1], acc);                                 \
        acc = fmaf(-b.z, hu[(j) & 1][0], acc);                                 \
        unsigned p = ((unsigned)t) & 1023u;                                    \
        if (lane_act) s_hist[p] = acc;                                         \
        unsigned pm = ((unsigned)((cc) * KC)) & 1023u;                         \
        if (pm >= 976u || pm < 7u) {                                           \
            if (lane_act && p < 7u) s_hist[p + 1024u] = acc;                   \
        }                                                                      \
        if (lane_act) out[t] = acc;                                            \
        int nb = __float_as_int(CF[((j) + 2) % DRING][1].w);                   \
        unsigned q = ((unsigned)(nb - 6)) & 1023u;                             \
        hu[(j) & 1][0] = s_hist[q + 0];                                        \
        hu[(j) & 1][1] = s_hist[q + 1];                                        \
        hu[(j) & 1][2] = s_hist[q + 2];                                        \
        hu[(j) & 1][3] = s_hist[q + 3];                                        \
        hu[(j) & 1][4] = s_hist[q + 4];                                        \
        hu[(j) & 1][5] = s_hist[q + 5];                                        \
        hu[(j) & 1][6] = s_hist[q + 6];                                        \
        int tc = ((cc) + DRING) * KC + lane;                                   \
        if (tc > T_SAMPLES - 1) tc = T_SAMPLES - 1;                            \
        CF[j][0] = cw[tc * 2 + 0];                                             \
        CF[j][1] = cw[tc * 2 + 1];                                             \
    }

    // bodies 0..47: excitation mix active (t0 <= 47*49 = 2303)
    for (int cb = 0; cb < 48; cb += DRING) {
        #pragma unroll
        for (int j = 0; j < DRING; ++j) KS_BODY(cb + j, j, true);
    }
    // bodies 48..899: steady state
    for (int cb = 48; cb < NB; cb += DRING) {
        #pragma unroll
        for (int j = 0; j < DRING; ++j) KS_BODY(cb + j, j, false);
    }
    #undef KS_BODY
}

// ------------------------------------------------- fallback (round-1 kernel)
#define CHUNK_FB  101
#define NCH_FB    ((T_SAMPLES + CHUNK_FB - 1) / CHUNK_FB)
#define HIST_FB   1024

__global__ __launch_bounds__(128) void diffks_fallback(
    const float* __restrict__ delay_frames,
    const float* __restrict__ excitation,
    const float* __restrict__ raw_coeff,
    const float* __restrict__ raw_gain,
    const float* __restrict__ exc_coeff,
    float* __restrict__ out)
{
    __shared__ float s_a[EXC_ORD][BURST];
    __shared__ float s_x[BURST];
    __shared__ float s_hist[HIST_FB];
    __shared__ __align__(16) float s_coef[NFRAMES][8];
    __shared__ float s_delay[NFRAMES];

    const int tid = threadIdx.x;
    const float gain = 0.1f / (1.0f + expf(-raw_gain[0])) + 0.9f;

    for (int i = tid; i < NFRAMES; i += 128) s_delay[i] = delay_frames[i];
    for (int f = tid; f < NFRAMES; f += 128) {
        float sb[NCOEF]; float s = 0.0f;
        #pragma unroll
        for (int j = 0; j < NCOEF; ++j) {
            sb[j] = 1.0f / (1.0f + expf(-raw_coeff[f * NCOEF + j]));
            s += sb[j];
        }
        float inv = gain / s;
        #pragma unroll
        for (int j = 0; j < NCOEF; ++j) s_coef[f][j] = sb[j] * inv;
        s_coef[f][6] = 0.0f; s_coef[f][7] = 0.0f;
    }
    const float stepE = 99.0f / 2047.0f;
    for (int t = tid; t < BURST; t += 128) {
        float pos = (float)t * stepE;
        int i0 = (int)pos; if (i0 > NFRAMES - 2) i0 = NFRAMES - 2;
        float w = pos - (float)i0;
        const float* c0 = exc_coeff + i0 * EXC_ORD;
        #pragma unroll
        for (int k = 0; k < EXC_ORD; ++k) {
            float a0 = c0[k], a1 = c0[k + EXC_ORD];
            s_a[k][t] = a0 + (a1 - a0) * w;
        }
        s_x[t] = excitation[t];
    }
    for (int i = tid; i < HIST_FB; i += 128) s_hist[i] = 0.0f;
    __syncthreads();

    if (tid == 0) {
        float y1 = 0.f, y2 = 0.f, y3 = 0.f, y4 = 0.f, y5 = 0.f;
        #pragma unroll 4
        for (int t = 0; t < BURST; ++t) {
            float p = s_x[t];
            p = fmaf(-s_a[1][t], y2, p);
            p = fmaf(-s_a[2][t], y3, p);
            p = fmaf(-s_a[3][t], y4, p);
            p = fmaf(-s_a[4][t], y5, p);
            float y = fmaf(-s_a[0][t], y1, p);
            s_x[t] = y;
            y5 = y4; y4 = y3; y3 = y2; y2 = y1; y1 = y;
        }
    }
    __syncthreads();

    const float stepT = 99.0f / (float)(T_SAMPLES - 1);
    for (int c = 0; c < NCH_FB; ++c) {
        int t = c * CHUNK_FB + tid;
        if (tid < CHUNK_FB && t < T_SAMPLES) {
            float pos = (float)t * stepT;
            int i0 = (int)pos; if (i0 > NFRAMES - 2) i0 = NFRAMES - 2;
            float w = pos - (float)i0;
            float d0 = s_delay[i0], d1 = s_delay[i0 + 1];
            float delay = d0 + (d1 - d0) * w;
            int z = (int)delay;
            float alfa = delay - (float)z;
            const float4* f0 = reinterpret_cast<const float4*>(s_coef[i0]);
            const float4* f1 = reinterpret_cast<const float4*>(s_coef[i0 + 1]);
            float4 c0a = f0[0], c0b = f0[1];
            float4 c1a = f1[0], c1b = f1[1];
            float b[NCOEF];
            b[0] = c0a.x + (c1a.x - c0a.x) * w;
            b[1] = c0a.y + (c1a.y - c0a.y) * w;
            b[2] = c0a.z + (c1a.z - c0a.z) * w;
            b[3] = c0a.w + (c1a.w - c0a.w) * w;
            b[4] = c0b.x + (c1b.x - c0b.x) * w;
            b[5] = c0b.y + (c1b.y - c0b.y) * w;
            float oma = 1.0f - alfa;
            float v[NACT];
            v[0] = -oma * b[0];
            #pragma unroll
            for (int j = 1; j <= 5; ++j) v[j] = -(alfa * b[j - 1] + oma * b[j]);
            v[6] = -alfa * b[5];
            float x = (t < BURST) ? s_x[t] : 0.0f;
            int base = t - z - 1;
            float sum = 0.0f;
            #pragma unroll
            for (int j = 0; j < NACT; ++j) {
                int idx = base - j;
                float yv = s_hist[idx & (HIST_FB - 1)];
                if (idx < 0) yv = 0.0f;
                sum = fmaf(v[j], yv, sum);
            }
            float y = x - sum;
            s_hist[t & (HIST_FB - 1)] = y;
            out[t] = y;
        }
        __syncthreads();
    }
}

// ---------------------------------------------------------------- launch
extern "C" void kernel_launch(void* const* d_in, const int* in_sizes, int n_in,
                              void* d_out, int out_size, void* d_ws, size_t ws_size,
                              hipStream_t stream) {
    const float* delay_frames = (const float*)d_in[0];
    const float* excitation   = (const float*)d_in[1];
    const float* raw_coeff    = (const float*)d_in[2];
    const float* raw_gain     = (const float*)d_in[3];
    const float* exc_coeff    = (const float*)d_in[4];
    float* out = (float*)d_out;

    if (ws_size >= WS_TOTAL_BYTES) {
        float* ws = (float*)d_ws;
        int gridA = (T_SAMPLES + BURST + 255) / 256;
        diffks_precompute<<<gridA, 256, 0, stream>>>(delay_frames, raw_coeff,
                                                     raw_gain, exc_coeff, ws);
        diffks_serial<<<1, 64, 0, stream>>>(excitation, ws, out);
    } else {
        diffks_fallback<<<1, 128, 0, stream>>>(delay_frames, excitation,
                                               raw_coeff, raw_gain, exc_coeff, out);
    }
}